// Round 1
// baseline (404.222 us; speedup 1.0000x reference)
//
#include <hip/hip_runtime.h>

#define HDIM 256
#define LN_EPS 1e-5f

// ---------------------------------------------------------------------------
// Kernel 1: per-batch fused GEMV chain
//   v    = vision @ Wv.T + bv                (512 -> 256)
//   v2   = v @ Wiv.T + biv   (Wiv = in_proj_w[512:], biv = in_proj_b[512:])
//   attn = v2 @ Wo.T + bo                    (256 -> 256)
//   proj = attn @ Wout.T + bout              (256 -> 768)
// grid = 32 (one block per batch), block = 256
// ---------------------------------------------------------------------------
__global__ __launch_bounds__(256) void proj_chain_kernel(
    const float* __restrict__ vision,     // (32,512)
    const float* __restrict__ Wv,         // (256,512)
    const float* __restrict__ bv,         // (256)
    const float* __restrict__ in_proj_w,  // (768,256)
    const float* __restrict__ in_proj_b,  // (768)
    const float* __restrict__ Wo,         // (256,256)
    const float* __restrict__ bo,         // (256)
    const float* __restrict__ Wout,       // (768,256)
    const float* __restrict__ bout,       // (768)
    float* __restrict__ proj)             // (32,768) output
{
    __shared__ float vis[512];
    __shared__ float v[HDIM];
    __shared__ float v2[HDIM];
    __shared__ float attn[HDIM];

    const int b = blockIdx.x;
    const int t = threadIdx.x;

    // stage vision row into LDS (128 float4s)
    if (t < 128) {
        ((float4*)vis)[t] = ((const float4*)(vision + (size_t)b * 512))[t];
    }
    __syncthreads();

    // v[t] = bv[t] + dot(vis, Wv[t,:])   K=512
    {
        const float4* w = (const float4*)(Wv + (size_t)t * 512);
        const float4* x = (const float4*)vis;
        float acc = bv[t];
        #pragma unroll 8
        for (int j = 0; j < 128; ++j) {
            float4 wv = w[j], xv = x[j];
            acc += wv.x * xv.x + wv.y * xv.y + wv.z * xv.z + wv.w * xv.w;
        }
        v[t] = acc;
    }
    __syncthreads();

    // v2[t] = biv[t] + dot(v, Wiv[t,:])  K=256, Wiv row t = in_proj_w[(512+t),:]
    {
        const float4* w = (const float4*)(in_proj_w + (size_t)(512 + t) * 256);
        const float4* x = (const float4*)v;
        float acc = in_proj_b[512 + t];
        #pragma unroll 8
        for (int j = 0; j < 64; ++j) {
            float4 wv = w[j], xv = x[j];
            acc += wv.x * xv.x + wv.y * xv.y + wv.z * xv.z + wv.w * xv.w;
        }
        v2[t] = acc;
    }
    __syncthreads();

    // attn[t] = bo[t] + dot(v2, Wo[t,:]) K=256
    {
        const float4* w = (const float4*)(Wo + (size_t)t * 256);
        const float4* x = (const float4*)v2;
        float acc = bo[t];
        #pragma unroll 8
        for (int j = 0; j < 64; ++j) {
            float4 wv = w[j], xv = x[j];
            acc += wv.x * xv.x + wv.y * xv.y + wv.z * xv.z + wv.w * xv.w;
        }
        attn[t] = acc;
    }
    __syncthreads();

    // proj[b, m] = bout[m] + dot(attn, Wout[m,:]), m = t, t+256, t+512
    #pragma unroll
    for (int mi = 0; mi < 3; ++mi) {
        const int m = t + mi * 256;
        const float4* w = (const float4*)(Wout + (size_t)m * 256);
        const float4* x = (const float4*)attn;
        float acc = bout[m];
        #pragma unroll 8
        for (int j = 0; j < 64; ++j) {
            float4 wv = w[j], xv = x[j];
            acc += wv.x * xv.x + wv.y * xv.y + wv.z * xv.z + wv.w * xv.w;
        }
        proj[(size_t)b * 768 + m] = acc;
    }
}

// ---------------------------------------------------------------------------
// Kernel 2: x = audio + proj[b] broadcast, then LayerNorm over last dim (768)
// One wave (64 lanes) per row; 3 float4 per lane = 768 floats.
// grid = 32*2048/4 = 16384 blocks of 256 threads (4 waves/block).
// ---------------------------------------------------------------------------
__global__ __launch_bounds__(256) void add_ln_kernel(
    const float* __restrict__ audio,   // (32,2048,768)
    const float* __restrict__ proj,    // (32,768)
    const float* __restrict__ gamma,   // (768)
    const float* __restrict__ beta,    // (768)
    float* __restrict__ out)           // (32,2048,768)
{
    const int wave = threadIdx.x >> 6;
    const int lane = threadIdx.x & 63;
    const long long row = (long long)blockIdx.x * 4 + wave;   // 0..65535
    const int b = (int)(row >> 11);                            // row / 2048

    const float4* a  = (const float4*)(audio + row * 768);
    const float4* p  = (const float4*)(proj + (size_t)b * 768);
    const float4* g4 = (const float4*)gamma;
    const float4* be = (const float4*)beta;
    float4* o = (float4*)(out + row * 768);

    float4 xv[3];
    float sum = 0.f, sq = 0.f;
    #pragma unroll
    for (int i = 0; i < 3; ++i) {
        const int idx = lane + i * 64;
        float4 av = a[idx];
        float4 pv = p[idx];
        float4 x;
        x.x = av.x + pv.x;
        x.y = av.y + pv.y;
        x.z = av.z + pv.z;
        x.w = av.w + pv.w;
        xv[i] = x;
        sum += x.x + x.y + x.z + x.w;
        sq  += x.x * x.x + x.y * x.y + x.z * x.z + x.w * x.w;
    }

    // wave-wide butterfly reduction over 64 lanes
    #pragma unroll
    for (int off = 1; off < 64; off <<= 1) {
        sum += __shfl_xor(sum, off, 64);
        sq  += __shfl_xor(sq,  off, 64);
    }

    const float inv_n = 1.0f / 768.0f;
    const float mean = sum * inv_n;
    const float var  = sq * inv_n - mean * mean;
    const float rstd = rsqrtf(var + LN_EPS);

    #pragma unroll
    for (int i = 0; i < 3; ++i) {
        const int idx = lane + i * 64;
        float4 gv = g4[idx];
        float4 bv = be[idx];
        float4 x = xv[i];
        float4 y;
        y.x = (x.x - mean) * rstd * gv.x + bv.x;
        y.y = (x.y - mean) * rstd * gv.y + bv.y;
        y.z = (x.z - mean) * rstd * gv.z + bv.z;
        y.w = (x.w - mean) * rstd * gv.w + bv.w;
        o[idx] = y;
    }
}

extern "C" void kernel_launch(void* const* d_in, const int* in_sizes, int n_in,
                              void* d_out, int out_size, void* d_ws, size_t ws_size,
                              hipStream_t stream) {
    const float* audio      = (const float*)d_in[0];
    const float* vision     = (const float*)d_in[1];
    // d_in[2] Wq, d_in[3] bq, d_in[4] Wk, d_in[5] bk  -- unused by reference
    const float* Wv         = (const float*)d_in[6];
    const float* bv         = (const float*)d_in[7];
    const float* in_proj_w  = (const float*)d_in[8];
    const float* in_proj_b  = (const float*)d_in[9];
    const float* Wo_mha     = (const float*)d_in[10];
    const float* bo_mha     = (const float*)d_in[11];
    const float* Wout       = (const float*)d_in[12];
    const float* bout       = (const float*)d_in[13];
    const float* gamma      = (const float*)d_in[14];
    const float* beta       = (const float*)d_in[15];
    float* out = (float*)d_out;

    float* proj = (float*)d_ws;   // 32*768 fp32 = 96 KB scratch

    proj_chain_kernel<<<32, 256, 0, stream>>>(
        vision, Wv, bv, in_proj_w, in_proj_b, Wo_mha, bo_mha, Wout, bout, proj);

    add_ln_kernel<<<16384, 256, 0, stream>>>(audio, proj, gamma, beta, out);
}

// Round 3
// 401.778 us; speedup vs baseline: 1.0061x; 1.0061x over previous
//
#include <hip/hip_runtime.h>

#define HDIM 256
#define LN_EPS 1e-5f

// native clang vector type — required by __builtin_nontemporal_{load,store}
typedef float nfloat4 __attribute__((ext_vector_type(4)));

// ---------------------------------------------------------------------------
// Kernel 1: per-batch fused GEMV chain (latency-bound, ~µs; weights L2-resident)
//   v    = vision @ Wv.T + bv                (512 -> 256)
//   v2   = v @ Wiv.T + biv   (Wiv = in_proj_w[512:], biv = in_proj_b[512:])
//   attn = v2 @ Wo.T + bo                    (256 -> 256)
//   proj = attn @ Wout.T + bout              (256 -> 768)
// grid = 32 (one block per batch), block = 256
// ---------------------------------------------------------------------------
__global__ __launch_bounds__(256) void proj_chain_kernel(
    const float* __restrict__ vision,     // (32,512)
    const float* __restrict__ Wv,         // (256,512)
    const float* __restrict__ bv,         // (256)
    const float* __restrict__ in_proj_w,  // (768,256)
    const float* __restrict__ in_proj_b,  // (768)
    const float* __restrict__ Wo,         // (256,256)
    const float* __restrict__ bo,         // (256)
    const float* __restrict__ Wout,       // (768,256)
    const float* __restrict__ bout,       // (768)
    float* __restrict__ proj)             // (32,768) output
{
    __shared__ float vis[512];
    __shared__ float v[HDIM];
    __shared__ float v2[HDIM];
    __shared__ float attn[HDIM];

    const int b = blockIdx.x;
    const int t = threadIdx.x;

    if (t < 128) {
        ((float4*)vis)[t] = ((const float4*)(vision + (size_t)b * 512))[t];
    }
    __syncthreads();

    // v[t] = bv[t] + dot(vis, Wv[t,:])   K=512
    {
        const float4* w = (const float4*)(Wv + (size_t)t * 512);
        const float4* x = (const float4*)vis;
        float acc = bv[t];
        #pragma unroll 8
        for (int j = 0; j < 128; ++j) {
            float4 wv = w[j], xv = x[j];
            acc += wv.x * xv.x + wv.y * xv.y + wv.z * xv.z + wv.w * xv.w;
        }
        v[t] = acc;
    }
    __syncthreads();

    // v2[t] = biv[t] + dot(v, Wiv[t,:])  K=256
    {
        const float4* w = (const float4*)(in_proj_w + (size_t)(512 + t) * 256);
        const float4* x = (const float4*)v;
        float acc = in_proj_b[512 + t];
        #pragma unroll 8
        for (int j = 0; j < 64; ++j) {
            float4 wv = w[j], xv = x[j];
            acc += wv.x * xv.x + wv.y * xv.y + wv.z * xv.z + wv.w * xv.w;
        }
        v2[t] = acc;
    }
    __syncthreads();

    // attn[t] = bo[t] + dot(v2, Wo[t,:]) K=256
    {
        const float4* w = (const float4*)(Wo + (size_t)t * 256);
        const float4* x = (const float4*)v2;
        float acc = bo[t];
        #pragma unroll 8
        for (int j = 0; j < 64; ++j) {
            float4 wv = w[j], xv = x[j];
            acc += wv.x * xv.x + wv.y * xv.y + wv.z * xv.z + wv.w * xv.w;
        }
        attn[t] = acc;
    }
    __syncthreads();

    // proj[b, m] = bout[m] + dot(attn, Wout[m,:]), m = t, t+256, t+512
    #pragma unroll
    for (int mi = 0; mi < 3; ++mi) {
        const int m = t + mi * 256;
        const float4* w = (const float4*)(Wout + (size_t)m * 256);
        const float4* x = (const float4*)attn;
        float acc = bout[m];
        #pragma unroll 8
        for (int j = 0; j < 64; ++j) {
            float4 wv = w[j], xv = x[j];
            acc += wv.x * xv.x + wv.y * xv.y + wv.z * xv.z + wv.w * xv.w;
        }
        proj[(size_t)b * 768 + m] = acc;
    }
}

// ---------------------------------------------------------------------------
// Kernel 2: x = audio + proj[b] broadcast, then LayerNorm over last dim (768)
// One wave per row; 3 float4 per lane. Streaming arrays (audio, out) use
// non-temporal hints to avoid thrashing L2 (zero reuse); proj/gamma/beta stay
// cached (massive reuse).
// ---------------------------------------------------------------------------
__global__ __launch_bounds__(256) void add_ln_kernel(
    const float* __restrict__ audio,   // (32,2048,768)
    const float* __restrict__ proj,    // (32,768)
    const float* __restrict__ gamma,   // (768)
    const float* __restrict__ beta,    // (768)
    float* __restrict__ out)           // (32,2048,768)
{
    const int wave = threadIdx.x >> 6;
    const int lane = threadIdx.x & 63;
    const long long row = (long long)blockIdx.x * 4 + wave;   // 0..65535
    const int b = (int)(row >> 11);                            // row / 2048

    const nfloat4* a  = (const nfloat4*)(audio + row * 768);
    const float4*  p  = (const float4*)(proj + (size_t)b * 768);
    const float4*  g4 = (const float4*)gamma;
    const float4*  be = (const float4*)beta;
    nfloat4* o = (nfloat4*)(out + row * 768);

    nfloat4 xv[3];
    float sum = 0.f, sq = 0.f;
    #pragma unroll
    for (int i = 0; i < 3; ++i) {
        const int idx = lane + i * 64;
        nfloat4 av = __builtin_nontemporal_load(&a[idx]);
        float4 pv = p[idx];
        nfloat4 x;
        x.x = av.x + pv.x;
        x.y = av.y + pv.y;
        x.z = av.z + pv.z;
        x.w = av.w + pv.w;
        xv[i] = x;
        sum += x.x + x.y + x.z + x.w;
        sq  += x.x * x.x + x.y * x.y + x.z * x.z + x.w * x.w;
    }

    // wave-wide butterfly reduction over 64 lanes
    #pragma unroll
    for (int off = 1; off < 64; off <<= 1) {
        sum += __shfl_xor(sum, off, 64);
        sq  += __shfl_xor(sq,  off, 64);
    }

    const float inv_n = 1.0f / 768.0f;
    const float mean = sum * inv_n;
    const float var  = sq * inv_n - mean * mean;
    const float rstd = rsqrtf(var + LN_EPS);

    #pragma unroll
    for (int i = 0; i < 3; ++i) {
        const int idx = lane + i * 64;
        float4 gv = g4[idx];
        float4 bv = be[idx];
        nfloat4 x = xv[i];
        nfloat4 y;
        y.x = (x.x - mean) * rstd * gv.x + bv.x;
        y.y = (x.y - mean) * rstd * gv.y + bv.y;
        y.z = (x.z - mean) * rstd * gv.z + bv.z;
        y.w = (x.w - mean) * rstd * gv.w + bv.w;
        __builtin_nontemporal_store(y, &o[idx]);
    }
}

extern "C" void kernel_launch(void* const* d_in, const int* in_sizes, int n_in,
                              void* d_out, int out_size, void* d_ws, size_t ws_size,
                              hipStream_t stream) {
    const float* audio      = (const float*)d_in[0];
    const float* vision     = (const float*)d_in[1];
    // d_in[2..5] Wq, bq, Wk, bk -- unused by the reference (k, q never consumed)
    const float* Wv         = (const float*)d_in[6];
    const float* bv         = (const float*)d_in[7];
    const float* in_proj_w  = (const float*)d_in[8];
    const float* in_proj_b  = (const float*)d_in[9];
    const float* Wo_mha     = (const float*)d_in[10];
    const float* bo_mha     = (const float*)d_in[11];
    const float* Wout       = (const float*)d_in[12];
    const float* bout       = (const float*)d_in[13];
    const float* gamma      = (const float*)d_in[14];
    const float* beta       = (const float*)d_in[15];
    float* out = (float*)d_out;

    float* proj = (float*)d_ws;   // 32*768 fp32 = 96 KB scratch

    proj_chain_kernel<<<32, 256, 0, stream>>>(
        vision, Wv, bv, in_proj_w, in_proj_b, Wo_mha, bo_mha, Wout, bout, proj);

    add_ln_kernel<<<16384, 256, 0, stream>>>(audio, proj, gamma, beta, out);
}